// Round 4
// baseline (11.423 us; speedup 1.0000x reference)
//
#include <hip/hip_runtime.h>
#include <math.h>

#define BATCH 262144
#define NC 7

__global__ __launch_bounds__(256, 4)
void qcirc_kernel(const float* __restrict__ x_cont,
                  const float* __restrict__ x_cat,
                  const float* __restrict__ qw,
                  const float* __restrict__ head_w,
                  const float* __restrict__ head_b,
                  float* __restrict__ out)
{
    const int b = blockIdx.x * blockDim.x + threadIdx.x;

    // Issue data loads FIRST so HBM latency overlaps the leader's uniform math.
    const float4 c0 = *reinterpret_cast<const float4*>(x_cont + b * 8);
    const float4 c1 = *reinterpret_cast<const float4*>(x_cont + b * 8 + 4);
    const float4 xc = *reinterpret_cast<const float4*>(x_cat + b * 4);

    // 8 qweight-only coefficients: z = (cx0*cx2/ss) * (G.A + sx1 * G.B)
    __shared__ float CAB[8];

    if (threadIdx.x == 0) {
        // layer-2 full angles (kappa), w = 1..5
        float kcv[6], ksv[6];
#pragma unroll
        for (int w = 1; w < 6; ++w) {
            kcv[w] = __cosf(qw[6 + w]);
            ksv[w] = __sinf(qw[6 + w]);
        }
        // layer-1 full angles, only w in {0,1,3,5} matter (RX on 2,4 commutes
        // with the I/X letters that land there)
        const float c10 = __cosf(qw[0]), s10 = __sinf(qw[0]);
        const float c11 = __cosf(qw[1]), s11 = __sinf(qw[1]);
        const float c13 = __cosf(qw[3]), s13 = __sinf(qw[3]);
        const float c15 = __cosf(qw[5]), s15 = __sinf(qw[5]);

        const float t3[2] = {c13, -s13};
        const float t5[2] = {c15, -s15};
        const float zc0[2] = {c10, -s10};
        const float zc1[2] = {c11, -s11};
        const float yc0[2] = {s10, c10};
        const float yc1[2] = {s11, c11};
        const float k1[2] = {kcv[1], ksv[1]};
        const float k2[2] = {kcv[2], ksv[2]};
        const float k3[2] = {kcv[3], ksv[3]};
        const float k4[2] = {kcv[4], ksv[4]};
        const float k5[2] = {kcv[5], ksv[5]};

        // inner sum over (y3, y4=y3^m): qubit-3/5 letter coefficients
        float W[2][2][2];  // [m][y2][y5]
#pragma unroll
        for (int m = 0; m < 2; ++m)
#pragma unroll
            for (int y2 = 0; y2 < 2; ++y2)
#pragma unroll
                for (int y5 = 0; y5 < 2; ++y5) {
                    float acc = 0.f;
#pragma unroll
                    for (int y3 = 0; y3 < 2; ++y3) {
                        const int y4 = y3 ^ m;
                        float t = k3[y3] * k4[y4] * t3[y2 ^ y3] * t5[y4 ^ y5];
                        if ((y2 & y3) ^ (y4 & y5)) t = -t;
                        acc += t;
                    }
                    W[m][y2][y5] = acc;
                }

        // outer sum over (y1, y5) for each (pair = ZZ/YY, u2, m)
        float AB[2][2][2] = {};  // [m][pair][u2]
#pragma unroll
        for (int m = 0; m < 2; ++m)
#pragma unroll
            for (int u2 = 0; u2 < 2; ++u2)
#pragma unroll
                for (int y1 = 0; y1 < 2; ++y1)
#pragma unroll
                    for (int y5 = 0; y5 < 2; ++y5) {
                        const int y2 = y1 ^ u2;
                        float base = k1[y1] * k2[y2] * k5[y5] * W[m][y2][y5];
                        if (y5 && !y1) base = -base;  // (-1)^(y5 + y1*y5)
                        AB[m][0][u2] += base * zc0[y5] * zc1[y1 ^ y5];
                        AB[m][1][u2] += base * yc0[y5] * yc1[y1 ^ y5];
                    }

        // fold the factor 2 of GZZX / GYYI / GYYX into the coefficients
        CAB[0] = AB[0][0][0];
        CAB[1] = AB[0][0][1] * 2.f;
        CAB[2] = AB[0][1][0] * 2.f;
        CAB[3] = AB[0][1][1] * 2.f;
        CAB[4] = AB[1][0][0];
        CAB[5] = AB[1][0][1] * 2.f;
        CAB[6] = AB[1][1][0] * 2.f;
        CAB[7] = AB[1][1][1] * 2.f;
    }
    __syncthreads();

    // ---- data path: 4 sparse quadratic forms on raw a (normalize via 1/ss) ----
    const float a0 = c0.x, a1 = c0.y, a2 = c0.z, a3 = c0.w;
    const float a4 = c1.x, a5 = c1.y, a6 = c1.z, a7 = c1.w;

    const float p0 = a0 * a0, p1 = a1 * a1, p2 = a2 * a2, p3 = a3 * a3;
    const float p4 = a4 * a4, p5 = a5 * a5, p6 = a6 * a6, p7 = a7 * a7;
    const float s01 = p0 + p1, s23 = p2 + p3, s45 = p4 + p5, s67 = p6 + p7;
    const float ss = (s01 + s23) + (s45 + s67);

    const float gzz0 = (s01 + s67) - (s23 + s45);                    // <Z Z I>*ss
    const float gzz1 = (a0 * a1 + a6 * a7) - (a2 * a3 + a4 * a5);    // <Z Z X>*ss/2
    const float gyy0 = (a2 * a4 + a3 * a5) - (a0 * a6 + a1 * a7);    // <Y Y I>*ss/2
    const float gyy1 = (a2 * a5 + a3 * a4) - (a0 * a7 + a1 * a6);    // <Y Y X>*ss/2

    const float A0 = CAB[0], A1 = CAB[1], A2 = CAB[2], A3 = CAB[3];
    const float B0 = CAB[4], B1 = CAB[5], B2 = CAB[6], B3 = CAB[7];

    const float accA = gzz0 * A0 + gzz1 * A1 + gyy0 * A2 + gyy1 * A3;
    const float accB = gzz0 * B0 + gzz1 * B1 + gyy0 * B2 + gyy1 * B3;

    const float cx0 = __cosf(xc.x);
    const float sx1 = __sinf(xc.y);
    const float cx2 = __cosf(xc.z);

    const float z = cx0 * cx2 * __builtin_amdgcn_rcpf(ss) * fmaf(sx1, accB, accA);

    // ---- linear head ----
#pragma unroll
    for (int c = 0; c < NC; ++c) {
        out[b * NC + c] = fmaf(z, head_w[c], head_b[c]);
    }
}

extern "C" void kernel_launch(void* const* d_in, const int* in_sizes, int n_in,
                              void* d_out, int out_size, void* d_ws, size_t ws_size,
                              hipStream_t stream) {
    (void)in_sizes; (void)n_in; (void)out_size; (void)d_ws; (void)ws_size;
    const float* x_cont = (const float*)d_in[0];
    const float* x_cat  = (const float*)d_in[1];
    const float* qw     = (const float*)d_in[2];
    const float* head_w = (const float*)d_in[3];
    const float* head_b = (const float*)d_in[4];
    float* out = (float*)d_out;

    const int threads = 256;
    const int blocks = BATCH / threads;  // 1024
    qcirc_kernel<<<blocks, threads, 0, stream>>>(x_cont, x_cat, qw, head_w, head_b, out);
}

// Round 5
// 10.050 us; speedup vs baseline: 1.1366x; 1.1366x over previous
//
#include <hip/hip_runtime.h>
#include <math.h>

#define BATCH 262144
#define NC 7

__global__ __launch_bounds__(256, 4)
void qcirc_kernel(const float* __restrict__ x_cont,
                  const float* __restrict__ x_cat,
                  const float* __restrict__ qw,
                  const float* __restrict__ head_w,
                  const float* __restrict__ head_b,
                  float* __restrict__ out)
{
    const int t = threadIdx.x;
    const int b = blockIdx.x * 256 + t;

    // Issue data loads FIRST so HBM latency overlaps the leader's uniform math.
    const float4 c0 = *reinterpret_cast<const float4*>(x_cont + b * 8);
    const float4 c1 = *reinterpret_cast<const float4*>(x_cont + b * 8 + 4);
    const float4 xc = *reinterpret_cast<const float4*>(x_cat + b * 4);

    // 8 qweight-only coefficients: z = (cx0*cx2/ss) * (G.A + sx1 * G.B)
    __shared__ float CAB[8];
    __shared__ float HW[8];
    __shared__ float HB[8];
    __shared__ float ZL[256];

    if (t < 7) { HW[t] = head_w[t]; HB[t] = head_b[t]; }

    if (t == 0) {
        // layer-2 full angles (kappa), w = 1..5
        float kcv[6], ksv[6];
#pragma unroll
        for (int w = 1; w < 6; ++w) {
            kcv[w] = __cosf(qw[6 + w]);
            ksv[w] = __sinf(qw[6 + w]);
        }
        // layer-1 full angles, only w in {0,1,3,5} matter (RX on 2,4 commutes
        // with the I/X letters that land there)
        const float c10 = __cosf(qw[0]), s10 = __sinf(qw[0]);
        const float c11 = __cosf(qw[1]), s11 = __sinf(qw[1]);
        const float c13 = __cosf(qw[3]), s13 = __sinf(qw[3]);
        const float c15 = __cosf(qw[5]), s15 = __sinf(qw[5]);

        const float t3[2] = {c13, -s13};
        const float t5[2] = {c15, -s15};
        const float zc0[2] = {c10, -s10};
        const float zc1[2] = {c11, -s11};
        const float yc0[2] = {s10, c10};
        const float yc1[2] = {s11, c11};
        const float k1[2] = {kcv[1], ksv[1]};
        const float k2[2] = {kcv[2], ksv[2]};
        const float k3[2] = {kcv[3], ksv[3]};
        const float k4[2] = {kcv[4], ksv[4]};
        const float k5[2] = {kcv[5], ksv[5]};

        // inner sum over (y3, y4=y3^m): qubit-3/5 letter coefficients
        float W[2][2][2];  // [m][y2][y5]
#pragma unroll
        for (int m = 0; m < 2; ++m)
#pragma unroll
            for (int y2 = 0; y2 < 2; ++y2)
#pragma unroll
                for (int y5 = 0; y5 < 2; ++y5) {
                    float acc = 0.f;
#pragma unroll
                    for (int y3 = 0; y3 < 2; ++y3) {
                        const int y4 = y3 ^ m;
                        float tt = k3[y3] * k4[y4] * t3[y2 ^ y3] * t5[y4 ^ y5];
                        if ((y2 & y3) ^ (y4 & y5)) tt = -tt;
                        acc += tt;
                    }
                    W[m][y2][y5] = acc;
                }

        // outer sum over (y1, y5) for each (pair = ZZ/YY, u2, m)
        float AB[2][2][2] = {};  // [m][pair][u2]
#pragma unroll
        for (int m = 0; m < 2; ++m)
#pragma unroll
            for (int u2 = 0; u2 < 2; ++u2)
#pragma unroll
                for (int y1 = 0; y1 < 2; ++y1)
#pragma unroll
                    for (int y5 = 0; y5 < 2; ++y5) {
                        const int y2 = y1 ^ u2;
                        float base = k1[y1] * k2[y2] * k5[y5] * W[m][y2][y5];
                        if (y5 && !y1) base = -base;  // (-1)^(y5 + y1*y5)
                        AB[m][0][u2] += base * zc0[y5] * zc1[y1 ^ y5];
                        AB[m][1][u2] += base * yc0[y5] * yc1[y1 ^ y5];
                    }

        // fold the factor 2 of GZZX / GYYI / GYYX into the coefficients
        CAB[0] = AB[0][0][0];
        CAB[1] = AB[0][0][1] * 2.f;
        CAB[2] = AB[0][1][0] * 2.f;
        CAB[3] = AB[0][1][1] * 2.f;
        CAB[4] = AB[1][0][0];
        CAB[5] = AB[1][0][1] * 2.f;
        CAB[6] = AB[1][1][0] * 2.f;
        CAB[7] = AB[1][1][1] * 2.f;
    }
    __syncthreads();

    // ---- data path: 4 sparse quadratic forms on raw a (normalize via 1/ss) ----
    const float a0 = c0.x, a1 = c0.y, a2 = c0.z, a3 = c0.w;
    const float a4 = c1.x, a5 = c1.y, a6 = c1.z, a7 = c1.w;

    const float p0 = a0 * a0, p1 = a1 * a1, p2 = a2 * a2, p3 = a3 * a3;
    const float p4 = a4 * a4, p5 = a5 * a5, p6 = a6 * a6, p7 = a7 * a7;
    const float s01 = p0 + p1, s23 = p2 + p3, s45 = p4 + p5, s67 = p6 + p7;
    const float ss = (s01 + s23) + (s45 + s67);

    const float gzz0 = (s01 + s67) - (s23 + s45);                    // <Z Z I>*ss
    const float gzz1 = (a0 * a1 + a6 * a7) - (a2 * a3 + a4 * a5);    // <Z Z X>*ss/2
    const float gyy0 = (a2 * a4 + a3 * a5) - (a0 * a6 + a1 * a7);    // <Y Y I>*ss/2
    const float gyy1 = (a2 * a5 + a3 * a4) - (a0 * a7 + a1 * a6);    // <Y Y X>*ss/2

    const float A0 = CAB[0], A1 = CAB[1], A2 = CAB[2], A3 = CAB[3];
    const float B0 = CAB[4], B1 = CAB[5], B2 = CAB[6], B3 = CAB[7];

    const float accA = gzz0 * A0 + gzz1 * A1 + gyy0 * A2 + gyy1 * A3;
    const float accB = gzz0 * B0 + gzz1 * B1 + gyy0 * B2 + gyy1 * B3;

    const float cx0 = __cosf(xc.x);
    const float sx1 = __sinf(xc.y);
    const float cx2 = __cosf(xc.z);

    ZL[t] = cx0 * cx2 * __builtin_amdgcn_rcpf(ss) * fmaf(sx1, accB, accA);
    __syncthreads();

    // ---- coalesced epilogue: block writes its contiguous 1792-float span ----
    // as 448 float4 stores (256 by all threads + 192 by t<192).
    float* outb = out + (size_t)blockIdx.x * 1792;
#pragma unroll
    for (int rep = 0; rep < 2; ++rep) {
        const int i = rep * 256 + t;
        if (rep == 0 || t < 192) {
            float4 v;
#pragma unroll
            for (int k = 0; k < 4; ++k) {
                const int f = 4 * i + k;
                const int bl = f / 7;        // magic-multiply, no HW divide
                const int c = f - bl * 7;
                (&v.x)[k] = fmaf(ZL[bl], HW[c], HB[c]);
            }
            *reinterpret_cast<float4*>(outb + 4 * i) = v;
        }
    }
}

extern "C" void kernel_launch(void* const* d_in, const int* in_sizes, int n_in,
                              void* d_out, int out_size, void* d_ws, size_t ws_size,
                              hipStream_t stream) {
    (void)in_sizes; (void)n_in; (void)out_size; (void)d_ws; (void)ws_size;
    const float* x_cont = (const float*)d_in[0];
    const float* x_cat  = (const float*)d_in[1];
    const float* qw     = (const float*)d_in[2];
    const float* head_w = (const float*)d_in[3];
    const float* head_b = (const float*)d_in[4];
    float* out = (float*)d_out;

    const int threads = 256;
    const int blocks = BATCH / threads;  // 1024
    qcirc_kernel<<<blocks, threads, 0, stream>>>(x_cont, x_cat, qw, head_w, head_b, out);
}

// Round 7
// 9.999 us; speedup vs baseline: 1.1425x; 1.0052x over previous
//
#include <hip/hip_runtime.h>
#include <math.h>

#define BATCH 262144
#define NC 7

typedef float floatx4 __attribute__((ext_vector_type(4)));

__global__ __launch_bounds__(256, 4)
void qcirc_kernel(const float* __restrict__ x_cont,
                  const float* __restrict__ x_cat,
                  const float* __restrict__ qw,
                  const float* __restrict__ head_w,
                  const float* __restrict__ head_b,
                  float* __restrict__ out)
{
    const int t = threadIdx.x;
    const int w = t >> 6;        // wave id in block
    const int l = t & 63;        // lane id
    const int b = blockIdx.x * 256 + t;

    // Issue data loads FIRST so memory latency overlaps the uniform math.
    const float4 c0 = *reinterpret_cast<const float4*>(x_cont + b * 8);
    const float4 c1 = *reinterpret_cast<const float4*>(x_cont + b * 8 + 4);
    const float4 xc = *reinterpret_cast<const float4*>(x_cat + b * 4);

    // Wave-local LDS (no cross-wave deps -> NO barriers anywhere).
    __shared__ float  ZL[256];      // z per element, wave w owns [64w, 64w+64)
    __shared__ float2 HWB[4][8];    // per-wave copy of (head_w, head_b)

    if (l < 7) HWB[w][l] = make_float2(head_w[l], head_b[l]);

    // ---- wave-uniform coefficient computation, redundantly in ALL threads ----
    // (rounds 3->4 proved VALU is ~free here; this removes the serial leader
    //  chain and barrier #1)
    float CAB[8];
    {
        float kcv[6], ksv[6];
#pragma unroll
        for (int ww = 1; ww < 6; ++ww) {
            kcv[ww] = __cosf(qw[6 + ww]);
            ksv[ww] = __sinf(qw[6 + ww]);
        }
        const float c10 = __cosf(qw[0]), s10 = __sinf(qw[0]);
        const float c11 = __cosf(qw[1]), s11 = __sinf(qw[1]);
        const float c13 = __cosf(qw[3]), s13 = __sinf(qw[3]);
        const float c15 = __cosf(qw[5]), s15 = __sinf(qw[5]);

        const float t3[2] = {c13, -s13};
        const float t5[2] = {c15, -s15};
        const float zc0[2] = {c10, -s10};
        const float zc1[2] = {c11, -s11};
        const float yc0[2] = {s10, c10};
        const float yc1[2] = {s11, c11};
        const float k1[2] = {kcv[1], ksv[1]};
        const float k2[2] = {kcv[2], ksv[2]};
        const float k3[2] = {kcv[3], ksv[3]};
        const float k4[2] = {kcv[4], ksv[4]};
        const float k5[2] = {kcv[5], ksv[5]};

        float W[2][2][2];  // [m][y2][y5]
#pragma unroll
        for (int m = 0; m < 2; ++m)
#pragma unroll
            for (int y2 = 0; y2 < 2; ++y2)
#pragma unroll
                for (int y5 = 0; y5 < 2; ++y5) {
                    float acc = 0.f;
#pragma unroll
                    for (int y3 = 0; y3 < 2; ++y3) {
                        const int y4 = y3 ^ m;
                        float tt = k3[y3] * k4[y4] * t3[y2 ^ y3] * t5[y4 ^ y5];
                        if ((y2 & y3) ^ (y4 & y5)) tt = -tt;
                        acc += tt;
                    }
                    W[m][y2][y5] = acc;
                }

        float AB[2][2][2] = {};  // [m][pair][u2]
#pragma unroll
        for (int m = 0; m < 2; ++m)
#pragma unroll
            for (int u2 = 0; u2 < 2; ++u2)
#pragma unroll
                for (int y1 = 0; y1 < 2; ++y1)
#pragma unroll
                    for (int y5 = 0; y5 < 2; ++y5) {
                        const int y2 = y1 ^ u2;
                        float base = k1[y1] * k2[y2] * k5[y5] * W[m][y2][y5];
                        if (y5 && !y1) base = -base;  // (-1)^(y5 + y1*y5)
                        AB[m][0][u2] += base * zc0[y5] * zc1[y1 ^ y5];
                        AB[m][1][u2] += base * yc0[y5] * yc1[y1 ^ y5];
                    }

        CAB[0] = AB[0][0][0];
        CAB[1] = AB[0][0][1] * 2.f;
        CAB[2] = AB[0][1][0] * 2.f;
        CAB[3] = AB[0][1][1] * 2.f;
        CAB[4] = AB[1][0][0];
        CAB[5] = AB[1][0][1] * 2.f;
        CAB[6] = AB[1][1][0] * 2.f;
        CAB[7] = AB[1][1][1] * 2.f;
    }

    // ---- data path: 4 sparse quadratic forms on raw a (normalize via 1/ss) ----
    const float a0 = c0.x, a1 = c0.y, a2 = c0.z, a3 = c0.w;
    const float a4 = c1.x, a5 = c1.y, a6 = c1.z, a7 = c1.w;

    const float p0 = a0 * a0, p1 = a1 * a1, p2 = a2 * a2, p3 = a3 * a3;
    const float p4 = a4 * a4, p5 = a5 * a5, p6 = a6 * a6, p7 = a7 * a7;
    const float s01 = p0 + p1, s23 = p2 + p3, s45 = p4 + p5, s67 = p6 + p7;
    const float ss = (s01 + s23) + (s45 + s67);

    const float gzz0 = (s01 + s67) - (s23 + s45);                    // <Z Z I>*ss
    const float gzz1 = (a0 * a1 + a6 * a7) - (a2 * a3 + a4 * a5);    // <Z Z X>*ss/2
    const float gyy0 = (a2 * a4 + a3 * a5) - (a0 * a6 + a1 * a7);    // <Y Y I>*ss/2
    const float gyy1 = (a2 * a5 + a3 * a4) - (a0 * a7 + a1 * a6);    // <Y Y X>*ss/2

    const float accA = gzz0 * CAB[0] + gzz1 * CAB[1] + gyy0 * CAB[2] + gyy1 * CAB[3];
    const float accB = gzz0 * CAB[4] + gzz1 * CAB[5] + gyy0 * CAB[6] + gyy1 * CAB[7];

    const float cx0 = __cosf(xc.x);
    const float sx1 = __sinf(xc.y);
    const float cx2 = __cosf(xc.z);

    ZL[t] = cx0 * cx2 * __builtin_amdgcn_rcpf(ss) * fmaf(sx1, accB, accA);

    // ---- wave-local coalesced epilogue (same-wave LDS W->R: no barrier) ----
    // wave w writes output floats [blk*1792 + 448w, +448) as 112 float4:
    // slot j handled by lane l: j = l (all lanes) and j = 64 + l (l < 48).
    float* outw = out + (size_t)blockIdx.x * 1792 + w * 448;
#pragma unroll
    for (int rep = 0; rep < 2; ++rep) {
        const int j = rep * 64 + l;
        if (rep == 0 || l < 48) {
            floatx4 v;
#pragma unroll
            for (int k = 0; k < 4; ++k) {
                const int f = 4 * j + k;
                const int e = f / 7;           // element within wave (0..63)
                const int c = f - e * 7;       // class (0..6)
                const float  zz = ZL[(w << 6) + e];
                const float2 hh = HWB[w][c];
                v[k] = fmaf(zz, hh.x, hh.y);
            }
            __builtin_nontemporal_store(v, reinterpret_cast<floatx4*>(outw + 4 * j));
        }
    }
}

extern "C" void kernel_launch(void* const* d_in, const int* in_sizes, int n_in,
                              void* d_out, int out_size, void* d_ws, size_t ws_size,
                              hipStream_t stream) {
    (void)in_sizes; (void)n_in; (void)out_size; (void)d_ws; (void)ws_size;
    const float* x_cont = (const float*)d_in[0];
    const float* x_cat  = (const float*)d_in[1];
    const float* qw     = (const float*)d_in[2];
    const float* head_w = (const float*)d_in[3];
    const float* head_b = (const float*)d_in[4];
    float* out = (float*)d_out;

    const int threads = 256;
    const int blocks = BATCH / threads;  // 1024
    qcirc_kernel<<<blocks, threads, 0, stream>>>(x_cont, x_cat, qw, head_w, head_b, out);
}